// Round 7
// baseline (2246.139 us; speedup 1.0000x reference)
//
#include <hip/hip_runtime.h>
#include <hip/hip_bf16.h>

typedef __bf16 bf16_t;
typedef __bf16 bf16x8 __attribute__((ext_vector_type(8)));
typedef float f32x4 __attribute__((ext_vector_type(4)));

#define DI __device__ __forceinline__

static constexpr int TOK = 131072;  // 32 batches * 64*64 tokens
static constexpr int NWIN = 2048;   // 32 * 64 windows

// window-order token t -> source image token (LN1 gather) == proj scatter dest.
DI int src_token(int t) {
  int b = t >> 12;
  int widx = (t >> 6) & 63;
  int n = t & 63;
  int wh = widx >> 3, ww = widx & 7;
  int i = n >> 3, j = n & 7;
  int y = ((wh << 3) + i + 4) & 63;
  int x2 = ((ww << 3) + j + 4) & 63;
  return (b << 12) + (y << 6) + x2;
}

DI f32x4 mfma16(bf16x8 a, bf16x8 b, f32x4 c) {
  return __builtin_amdgcn_mfma_f32_16x16x32_bf16(a, b, c, 0, 0, 0);
}

// ---------------- weight transpose+convert: w[K][N] f32 -> wt[N][K] bf16 ----
__global__ void wconv_kernel(const float* __restrict__ w, bf16_t* __restrict__ wt,
                             int K, int N) {
  int idx = blockIdx.x * 256 + threadIdx.x;
  if (idx >= N * K) return;
  int n = idx / K, k = idx - n * K;
  wt[idx] = (bf16_t)w[(size_t)k * N + n];
}

// ---------------- LayerNorm (+optional shift/partition gather), f32 -> bf16 --
template <int MAP>
__global__ __launch_bounds__(256)
void ln_kernel(const float* __restrict__ xin, const float* __restrict__ g,
               const float* __restrict__ be, bf16_t* __restrict__ out) {
  int w = threadIdx.x >> 6, l = threadIdx.x & 63;
  int t = blockIdx.x * 4 + w;
  int s = MAP ? src_token(t) : t;
  const float* row = xin + (size_t)s * 384;
  float v[6], s1 = 0.f, s2 = 0.f;
#pragma unroll
  for (int i = 0; i < 6; i++) {
    v[i] = row[l + i * 64];
    s1 += v[i];
    s2 += v[i] * v[i];
  }
#pragma unroll
  for (int o = 32; o; o >>= 1) {
    s1 += __shfl_xor(s1, o);
    s2 += __shfl_xor(s2, o);
  }
  float mean = s1 * (1.f / 384.f);
  float var = s2 * (1.f / 384.f) - mean * mean;
  float rs = rsqrtf(var + 1e-5f);
  bf16_t* orow = out + (size_t)t * 384;
#pragma unroll
  for (int i = 0; i < 6; i++) {
    int idx = l + i * 64;
    orow[idx] = (bf16_t)((v[i] - mean) * rs * g[idx] + be[idx]);
  }
}

// ---------------- gather GEMM: no LDS, no barriers ---------------------------
// Each wave owns a 64x64 C-tile; A/B MFMA fragments are loaded DIRECTLY from
// global (16B/lane gathers; 16x64B segments per load — same cache-line count
// as a coalesced 1KB load; panels are L2/L3-resident under the XCD swizzle).
// Waves are fully self-paced: sync is plain register deps (compiler-tracked).
// 4 waves/block in a 2x2 tile arrangement share A/B panels via L1.
// MODE 0: bf16 out. 1: bf16 gelu(out). 2: f32 scatter(src_token)+resid.
// MODE 3: f32 +resid (resid aliases outf; element owned by one thread).
template <int MODE>
__global__ __launch_bounds__(256, 3)
void gemm_gather(const bf16_t* __restrict__ A, const bf16_t* __restrict__ Wt,
                 const float* __restrict__ bias, int K, int ldout, int ncols,
                 bf16_t* outb, float* outf, const float* resid) {
  const int tid = threadIdx.x;
  const int l = tid & 63, w = tid >> 6;
  const int lr = l & 15, lq = l >> 4;
  // XCD-chunked bijective remap (nwg % 8 == 0)
  const int nwg = gridDim.x;
  const int orig = blockIdx.x;
  const int wgid = (orig & 7) * (nwg >> 3) + (orig >> 3);
  const int bn = wgid % ncols, bm = wgid / ncols;
  const int wr = w >> 1, wc = w & 1;
  const size_t row0 = (size_t)bm * 128 + wr * 64;
  const size_t col0 = (size_t)bn * 128 + wc * 64;

  // lane-constant base pointers for fragment gathers
  const bf16_t* pa = A + (row0 + lr) * K + lq * 8;
  const bf16_t* pb = Wt + (col0 + lr) * K + lq * 8;
  const size_t fstride = (size_t)16 * K;  // 16-row fragment-block stride

  f32x4 acc[4][4] = {};
  bf16x8 a0[4], b0[4], a1[4], b1[4];
  const int nk = K >> 5;  // 32-wide K-steps; even for all our K (12, 48)

  auto load = [&](bf16x8 (&fa)[4], bf16x8 (&fb)[4], int s) {
    const bf16_t* pas = pa + s * 32;
    const bf16_t* pbs = pb + s * 32;
#pragma unroll
    for (int f = 0; f < 4; f++) {
      fa[f] = *(const bf16x8*)(pas + f * fstride);
      fb[f] = *(const bf16x8*)(pbs + f * fstride);
    }
  };
  auto step = [&](bf16x8 (&fa)[4], bf16x8 (&fb)[4]) {
#pragma unroll
    for (int fi = 0; fi < 4; fi++)
#pragma unroll
      for (int fj = 0; fj < 4; fj++)
        acc[fi][fj] = mfma16(fa[fi], fb[fj], acc[fi][fj]);
  };

  // 2-stage register pipeline, named sets (static indexing)
  load(a0, b0, 0);
  for (int s = 0; s + 2 < nk; s += 2) {
    load(a1, b1, s + 1);
    step(a0, b0);
    load(a0, b0, s + 2);
    step(a1, b1);
  }
  load(a1, b1, nk - 1);
  step(a0, b0);
  step(a1, b1);

  // ---- epilogue (64x64 tile) ----
#pragma unroll
  for (int fi = 0; fi < 4; fi++) {
#pragma unroll
    for (int reg = 0; reg < 4; reg++) {
      int grow = (int)row0 + fi * 16 + lq * 4 + reg;
      size_t rbase;
      if constexpr (MODE == 2)
        rbase = (size_t)src_token(grow) * ldout;
      else
        rbase = (size_t)grow * ldout;
#pragma unroll
      for (int fj = 0; fj < 4; fj++) {
        int gcol = (int)col0 + fj * 16 + lr;
        float val = acc[fi][fj][reg] + bias[gcol];
        if constexpr (MODE == 0) {
          outb[rbase + gcol] = (bf16_t)val;
        } else if constexpr (MODE == 1) {
          val = 0.5f * val * (1.f + erff(val * 0.70710678118f));
          outb[rbase + gcol] = (bf16_t)val;
        } else {
          outf[rbase + gcol] = val + resid[rbase + gcol];
        }
      }
    }
  }
}

// ---------------- per-(window, head) attention (staged, swizzled) -----------
__global__ __launch_bounds__(64)
void attn_kernel(const bf16_t* __restrict__ qkv, const float* __restrict__ btab,
                 bf16_t* __restrict__ aout) {
  __shared__ __align__(16) bf16_t Qs[64 * 32];
  __shared__ __align__(16) bf16_t Ks[64 * 32];
  __shared__ __align__(16) bf16_t Vt[32 * 64];
  __shared__ __align__(16) bf16_t Ps[64 * 64];
  const int win = blockIdx.x, h = blockIdx.y;
  const int l = threadIdx.x, lr = l & 15, lq = l >> 4;

  {
    const bf16_t* qrow = qkv + ((size_t)win * 64 + l) * 1152 + h * 32;
#pragma unroll
    for (int c = 0; c < 4; c++) {
      *(bf16x8*)&Qs[l * 32 + c * 8] = *(const bf16x8*)&qrow[c * 8];
      *(bf16x8*)&Ks[l * 32 + c * 8] = *(const bf16x8*)&qrow[384 + c * 8];
    }
#pragma unroll
    for (int c = 0; c < 4; c++) {
      bf16x8 tv = *(const bf16x8*)&qrow[768 + c * 8];
#pragma unroll
      for (int e = 0; e < 8; e++) {
        int vr = c * 8 + e;
        Vt[vr * 64 + (l ^ ((vr & 7) << 3))] = tv[e];  // swizzled col
      }
    }
  }
  __syncthreads();

  // S = Q K^T  (64x64, K=32)
  f32x4 sacc[4][4] = {};
  {
    bf16x8 a[4], b[4];
#pragma unroll
    for (int fi = 0; fi < 4; fi++)
      a[fi] = *(const bf16x8*)&Qs[(fi * 16 + lr) * 32 + lq * 8];
#pragma unroll
    for (int fj = 0; fj < 4; fj++)
      b[fj] = *(const bf16x8*)&Ks[(fj * 16 + lr) * 32 + lq * 8];
#pragma unroll
    for (int fi = 0; fi < 4; fi++)
#pragma unroll
      for (int fj = 0; fj < 4; fj++)
        sacc[fi][fj] = mfma16(a[fi], b[fj], sacc[fi][fj]);
  }

  const int widx = win & 63;
  const int wh = widx >> 3, ww = widx & 7;
  const float scale = 0.17677669529663687f;  // 32^-0.5
#pragma unroll
  for (int fi = 0; fi < 4; fi++) {
#pragma unroll
    for (int reg = 0; reg < 4; reg++) {
      int row = fi * 16 + lq * 4 + reg;  // C/D: row=(l>>4)*4+reg (+fi*16)
      int i1 = row >> 3, j1 = row & 7;
      int ly1 = (wh == 7) ? (i1 >= 4 ? 2 : 1) : 0;
      int lx1 = (ww == 7) ? (j1 >= 4 ? 2 : 1) : 0;
      float vals[4], m = -1e30f;
#pragma unroll
      for (int fj = 0; fj < 4; fj++) {
        int col = fj * 16 + lr;  // C/D: col=l&15 (+fj*16)
        int i2 = col >> 3, j2 = col & 7;
        float v = sacc[fi][fj][reg] * scale +
                  btab[((i1 - i2 + 7) * 15 + (j1 - j2 + 7)) * 12 + h];
        int ly2 = (wh == 7) ? (i2 >= 4 ? 2 : 1) : 0;
        int lx2 = (ww == 7) ? (j2 >= 4 ? 2 : 1) : 0;
        if (ly1 != ly2 || lx1 != lx2) v -= 100.f;
        vals[fj] = v;
        m = fmaxf(m, v);
      }
#pragma unroll
      for (int o = 1; o < 16; o <<= 1) m = fmaxf(m, __shfl_xor(m, o));
      float ssum = 0.f;
#pragma unroll
      for (int fj = 0; fj < 4; fj++) {
        vals[fj] = __expf(vals[fj] - m);
        ssum += vals[fj];
      }
#pragma unroll
      for (int o = 1; o < 16; o <<= 1) ssum += __shfl_xor(ssum, o);
      float inv = 1.f / ssum;
      int sw = (row & 7) << 3;
#pragma unroll
      for (int fj = 0; fj < 4; fj++)
        Ps[row * 64 + ((fj * 16 + lr) ^ sw)] = (bf16_t)(vals[fj] * inv);
    }
  }
  __syncthreads();

  // O = P V  (64x32, K=64); swizzled Ps / Vt reads (conflict-free)
  f32x4 oacc[4][2] = {};
#pragma unroll
  for (int kc = 0; kc < 2; kc++) {
    bf16x8 pa[4], vb[2];
#pragma unroll
    for (int fi = 0; fi < 4; fi++) {
      int row = fi * 16 + lr;
      pa[fi] = *(const bf16x8*)&Ps[row * 64 + ((kc * 32 + lq * 8) ^ ((row & 7) << 3))];
    }
#pragma unroll
    for (int fj = 0; fj < 2; fj++) {
      int row = fj * 16 + lr;
      vb[fj] = *(const bf16x8*)&Vt[row * 64 + ((kc * 32 + lq * 8) ^ ((row & 7) << 3))];
    }
#pragma unroll
    for (int fi = 0; fi < 4; fi++)
#pragma unroll
      for (int fj = 0; fj < 2; fj++)
        oacc[fi][fj] = mfma16(pa[fi], vb[fj], oacc[fi][fj]);
  }
#pragma unroll
  for (int fi = 0; fi < 4; fi++)
#pragma unroll
    for (int reg = 0; reg < 4; reg++) {
      int row = fi * 16 + lq * 4 + reg;
      size_t rb = ((size_t)win * 64 + row) * 384 + h * 32;
#pragma unroll
      for (int fj = 0; fj < 2; fj++)
        aout[rb + fj * 16 + lr] = (bf16_t)oacc[fi][fj][reg];
    }
}

// ---------------------------------------------------------------------------
extern "C" void kernel_launch(void* const* d_in, const int* in_sizes, int n_in,
                              void* d_out, int out_size, void* d_ws, size_t ws_size,
                              hipStream_t stream) {
  (void)in_sizes; (void)n_in; (void)out_size; (void)ws_size;
  const float* x      = (const float*)d_in[0];
  const float* gamma1 = (const float*)d_in[1];
  const float* beta1  = (const float*)d_in[2];
  const float* w_qkv  = (const float*)d_in[3];
  const float* b_qkv  = (const float*)d_in[4];
  const float* btab   = (const float*)d_in[5];
  const float* w_proj = (const float*)d_in[6];
  const float* b_proj = (const float*)d_in[7];
  const float* gamma2 = (const float*)d_in[8];
  const float* beta2  = (const float*)d_in[9];
  const float* w_fc1  = (const float*)d_in[10];
  const float* b_fc1  = (const float*)d_in[11];
  const float* w_fc2  = (const float*)d_in[12];
  const float* b_fc2  = (const float*)d_in[13];
  float* out = (float*)d_out;

  char* ws = (char*)d_ws;
  size_t off = 0;
  auto alloc = [&](size_t bytes) {
    void* p = ws + off;
    off += (bytes + 255) & ~(size_t)255;
    return p;
  };
  bf16_t* wqkvT  = (bf16_t*)alloc((size_t)1152 * 384 * 2);
  bf16_t* wprojT = (bf16_t*)alloc((size_t)384 * 384 * 2);
  bf16_t* wfc1T  = (bf16_t*)alloc((size_t)1536 * 384 * 2);
  bf16_t* wfc2T  = (bf16_t*)alloc((size_t)384 * 1536 * 2);
  // qkv rows [TOK][1152] alias mlp hidden [TOK][1536]; lifetimes disjoint.
  char* big = (char*)alloc((size_t)TOK * 1536 * 2);
  bf16_t* bufA = (bf16_t*)big;  // qkv rows
  bf16_t* bufH = (bf16_t*)big;  // mlp hidden
  bf16_t* bufB = (bf16_t*)alloc((size_t)TOK * 384 * 2);  // ln1/attn/ln2 rows

  wconv_kernel<<<(1152 * 384 + 255) / 256, 256, 0, stream>>>(w_qkv, wqkvT, 384, 1152);
  wconv_kernel<<<(384 * 384 + 255) / 256, 256, 0, stream>>>(w_proj, wprojT, 384, 384);
  wconv_kernel<<<(384 * 1536 + 255) / 256, 256, 0, stream>>>(w_fc1, wfc1T, 384, 1536);
  wconv_kernel<<<(1536 * 384 + 255) / 256, 256, 0, stream>>>(w_fc2, wfc2T, 1536, 384);

  // LN1 + roll + window partition -> bufB [131072][384] bf16
  ln_kernel<1><<<TOK / 4, 256, 0, stream>>>(x, gamma1, beta1, bufB);
  // QKV: [131072,384] x [384,1152] -> bufA bf16   (grid 9*1024, %8==0)
  gemm_gather<0><<<9 * (TOK / 128), 256, 0, stream>>>(
      bufB, wqkvT, b_qkv, 384, 1152, 9, bufA, nullptr, nullptr);
  // windowed attention -> bufB [131072][384] bf16
  attn_kernel<<<dim3(NWIN, 12), 64, 0, stream>>>(bufA, btab, bufB);
  // proj + un-roll scatter + residual(x) -> out (x1, f32)  (grid 3*1024)
  gemm_gather<2><<<3 * (TOK / 128), 256, 0, stream>>>(
      bufB, wprojT, b_proj, 384, 384, 3, nullptr, out, x);
  // LN2 -> bufB bf16
  ln_kernel<0><<<TOK / 4, 256, 0, stream>>>(out, gamma2, beta2, bufB);
  // FC1 + exact GELU -> bufH [131072][1536] bf16  (grid 12*1024)
  gemm_gather<1><<<12 * (TOK / 128), 256, 0, stream>>>(
      bufB, wfc1T, b_fc1, 384, 1536, 12, bufH, nullptr, nullptr);
  // FC2 + residual(out, in-place) -> out  (grid 3*1024)
  gemm_gather<3><<<3 * (TOK / 128), 256, 0, stream>>>(
      bufH, wfc2T, b_fc2, 1536, 384, 3, nullptr, out, out);
}

// Round 8
// 1497.348 us; speedup vs baseline: 1.5001x; 1.5001x over previous
//
#include <hip/hip_runtime.h>
#include <hip/hip_bf16.h>

typedef __bf16 bf16_t;
typedef __bf16 bf16x8 __attribute__((ext_vector_type(8)));
typedef float f32x4 __attribute__((ext_vector_type(4)));

#define DI __device__ __forceinline__

static constexpr int TOK = 131072;  // 32 batches * 64*64 tokens
static constexpr int NWIN = 2048;   // 32 * 64 windows

// window-order token t -> source image token (LN1 gather) == proj scatter dest.
DI int src_token(int t) {
  int b = t >> 12;
  int widx = (t >> 6) & 63;
  int n = t & 63;
  int wh = widx >> 3, ww = widx & 7;
  int i = n >> 3, j = n & 7;
  int y = ((wh << 3) + i + 4) & 63;
  int x2 = ((ww << 3) + j + 4) & 63;
  return (b << 12) + (y << 6) + x2;
}

DI f32x4 mfma16(bf16x8 a, bf16x8 b, f32x4 c) {
  return __builtin_amdgcn_mfma_f32_16x16x32_bf16(a, b, c, 0, 0, 0);
}

DI void gload_lds16(const bf16_t* g, bf16_t* l) {
  __builtin_amdgcn_global_load_lds(
      (__attribute__((address_space(1))) void*)const_cast<bf16_t*>(g),
      (__attribute__((address_space(3))) void*)l, 16, 0, 0);
}

// ---------------- weight transpose+convert: w[K][N] f32 -> wt[N][K] bf16 ----
__global__ void wconv_kernel(const float* __restrict__ w, bf16_t* __restrict__ wt,
                             int K, int N) {
  int idx = blockIdx.x * 256 + threadIdx.x;
  if (idx >= N * K) return;
  int n = idx / K, k = idx - n * K;
  wt[idx] = (bf16_t)w[(size_t)k * N + n];
}

// ---------------- LayerNorm (+optional shift/partition gather), f32 -> bf16 --
template <int MAP>
__global__ __launch_bounds__(256)
void ln_kernel(const float* __restrict__ xin, const float* __restrict__ g,
               const float* __restrict__ be, bf16_t* __restrict__ out) {
  int w = threadIdx.x >> 6, l = threadIdx.x & 63;
  int t = blockIdx.x * 4 + w;
  int s = MAP ? src_token(t) : t;
  const float* row = xin + (size_t)s * 384;
  float v[6], s1 = 0.f, s2 = 0.f;
#pragma unroll
  for (int i = 0; i < 6; i++) {
    v[i] = row[l + i * 64];
    s1 += v[i];
    s2 += v[i] * v[i];
  }
#pragma unroll
  for (int o = 32; o; o >>= 1) {
    s1 += __shfl_xor(s1, o);
    s2 += __shfl_xor(s2, o);
  }
  float mean = s1 * (1.f / 384.f);
  float var = s2 * (1.f / 384.f) - mean * mean;
  float rs = rsqrtf(var + 1e-5f);
  bf16_t* orow = out + (size_t)t * 384;
#pragma unroll
  for (int i = 0; i < 6; i++) {
    int idx = l + i * 64;
    orow[idx] = (bf16_t)((v[i] - mean) * rs * g[idx] + be[idx]);
  }
}

// ---------------- GEMM: C[M][N] = A[M][K]*Wt[N][K]^T + bias ------------------
// Round-6 proven geometry (128x128 tile, BK=64, both-sides XOR swizzle, XCD
// chunked remap) + T3 minimum-2-phase pipeline: double-buffered LDS with
// statically-unrolled phases; stage(next buf) issued BEFORE ds_read+MFMA(cur)
// so global loads hide under compute; one barrier per K-tile; no manual
// waitcnt (compiler drains at barrier -> race-free). K-invariant LDS read
// offsets precomputed; staging addresses strength-reduced.
// MODE 0: bf16 out. 1: bf16 gelu(out). 2: f32 scatter(src_token)+resid.
// MODE 3: f32 +resid (resid aliases outf; element owned by one thread).
template <int MODE>
__global__ __launch_bounds__(256, 2)
void gemm_bt(const bf16_t* __restrict__ A, const bf16_t* __restrict__ Wt,
             const float* __restrict__ bias, int K, int ldout, int ncols,
             bf16_t* outb, float* outf, const float* resid) {
  __shared__ __align__(16) bf16_t Alds[2 * 128 * 64];
  __shared__ __align__(16) bf16_t Blds[2 * 128 * 64];
  const int tid = threadIdx.x;
  const int l = tid & 63, w = tid >> 6;
  const int lr = l & 15, lq = l >> 4;
  // XCD-chunked bijective remap (nwg % 8 == 0)
  const int nwg = gridDim.x;
  const int orig = blockIdx.x;
  const int wgid = (orig & 7) * (nwg >> 3) + (orig >> 3);
  const int bn = wgid % ncols, bm = wgid / ncols;
  const int wr = w >> 1, wc = w & 1;

  // staging source (lane-dependent, swizzle-inverted): row&7 == l>>3 here,
  // so the inverse-swizzled source column is lane-only.
  const int srow = w * 8 + (l >> 3);
  const int scol = ((l & 7) ^ (l >> 3)) << 3;
  const bf16_t* ga = A + ((size_t)bm * 128 + srow) * K + scol;
  const bf16_t* gb = Wt + ((size_t)bn * 128 + srow) * K + scol;
  const size_t k32 = (size_t)32 * K;

  // K-invariant LDS read element-offsets (swizzled)
  int aoff[8], boff[8];
#pragma unroll
  for (int fi = 0; fi < 4; fi++) {
    int ra = wr * 64 + fi * 16 + lr;
    int rb = wc * 64 + fi * 16 + lr;
#pragma unroll
    for (int ks = 0; ks < 2; ks++) {
      aoff[fi * 2 + ks] = ra * 64 + ((ks * 32 + lq * 8) ^ ((ra & 7) << 3));
      boff[fi * 2 + ks] = rb * 64 + ((ks * 32 + lq * 8) ^ ((rb & 7) << 3));
    }
  }

  f32x4 acc[4][4] = {};

  auto stage = [&](int bb) {  // bb: 0 or 8192 (compile-time after inline)
#pragma unroll
    for (int r = 0; r < 4; r++) {
      gload_lds16(ga + r * k32, &Alds[bb + r * 2048 + w * 512]);
      gload_lds16(gb + r * k32, &Blds[bb + r * 2048 + w * 512]);
    }
    ga += 64;
    gb += 64;
  };
  auto compute = [&](int bb) {
#pragma unroll
    for (int ks = 0; ks < 2; ks++) {
      bf16x8 af[4], bfr[4];
#pragma unroll
      for (int fi = 0; fi < 4; fi++)
        af[fi] = *(const bf16x8*)&Alds[bb + aoff[fi * 2 + ks]];
#pragma unroll
      for (int fj = 0; fj < 4; fj++)
        bfr[fj] = *(const bf16x8*)&Blds[bb + boff[fj * 2 + ks]];
#pragma unroll
      for (int fi = 0; fi < 4; fi++)
#pragma unroll
        for (int fj = 0; fj < 4; fj++)
          acc[fi][fj] = mfma16(af[fi], bfr[fj], acc[fi][fj]);
    }
  };

  const int nt = K >> 6;  // 6 or 24 (always even, >= 4)
  stage(0);
  __syncthreads();
  for (int t = 0; t + 2 < nt; t += 2) {
    stage(8192);       // next tile -> buf1, overlaps compute(buf0)
    compute(0);
    __syncthreads();   // buf1 landed; all waves done reading buf0
    stage(0);          // tile t+2 -> buf0, overlaps compute(buf1)
    compute(8192);
    __syncthreads();
  }
  stage(8192);         // last tile
  compute(0);
  __syncthreads();
  compute(8192);       // no trailing barrier needed

  // ---- epilogue ----
  float bv[4];
#pragma unroll
  for (int fj = 0; fj < 4; fj++)
    bv[fj] = bias[bn * 128 + wc * 64 + fj * 16 + lr];
#pragma unroll
  for (int fi = 0; fi < 4; fi++) {
#pragma unroll
    for (int reg = 0; reg < 4; reg++) {
      int grow = bm * 128 + wr * 64 + fi * 16 + lq * 4 + reg;
      size_t rbase;
      if constexpr (MODE == 2)
        rbase = (size_t)src_token(grow) * ldout;
      else
        rbase = (size_t)grow * ldout;
#pragma unroll
      for (int fj = 0; fj < 4; fj++) {
        int gcol = bn * 128 + wc * 64 + fj * 16 + lr;
        float val = acc[fi][fj][reg] + bv[fj];
        if constexpr (MODE == 0) {
          outb[rbase + gcol] = (bf16_t)val;
        } else if constexpr (MODE == 1) {
          // tanh-form GELU: x * sigmoid(1.59577(x + 0.044715 x^3))
          float z = -1.5957691216f * val * fmaf(0.044715f, val * val, 1.0f);
          val = val / (1.0f + __expf(z));
          outb[rbase + gcol] = (bf16_t)val;
        } else {
          outf[rbase + gcol] = val + resid[rbase + gcol];
        }
      }
    }
  }
}

// ---------------- per-(window, head) attention (staged, swizzled) -----------
__global__ __launch_bounds__(64)
void attn_kernel(const bf16_t* __restrict__ qkv, const float* __restrict__ btab,
                 bf16_t* __restrict__ aout) {
  __shared__ __align__(16) bf16_t Qs[64 * 32];
  __shared__ __align__(16) bf16_t Ks[64 * 32];
  __shared__ __align__(16) bf16_t Vt[32 * 64];
  __shared__ __align__(16) bf16_t Ps[64 * 64];
  const int win = blockIdx.x, h = blockIdx.y;
  const int l = threadIdx.x, lr = l & 15, lq = l >> 4;

  {
    const bf16_t* qrow = qkv + ((size_t)win * 64 + l) * 1152 + h * 32;
#pragma unroll
    for (int c = 0; c < 4; c++) {
      *(bf16x8*)&Qs[l * 32 + c * 8] = *(const bf16x8*)&qrow[c * 8];
      *(bf16x8*)&Ks[l * 32 + c * 8] = *(const bf16x8*)&qrow[384 + c * 8];
    }
#pragma unroll
    for (int c = 0; c < 4; c++) {
      bf16x8 tv = *(const bf16x8*)&qrow[768 + c * 8];
#pragma unroll
      for (int e = 0; e < 8; e++) {
        int vr = c * 8 + e;
        Vt[vr * 64 + (l ^ ((vr & 7) << 3))] = tv[e];  // swizzled col
      }
    }
  }
  __syncthreads();

  // S = Q K^T  (64x64, K=32)
  f32x4 sacc[4][4] = {};
  {
    bf16x8 a[4], b[4];
#pragma unroll
    for (int fi = 0; fi < 4; fi++)
      a[fi] = *(const bf16x8*)&Qs[(fi * 16 + lr) * 32 + lq * 8];
#pragma unroll
    for (int fj = 0; fj < 4; fj++)
      b[fj] = *(const bf16x8*)&Ks[(fj * 16 + lr) * 32 + lq * 8];
#pragma unroll
    for (int fi = 0; fi < 4; fi++)
#pragma unroll
      for (int fj = 0; fj < 4; fj++)
        sacc[fi][fj] = mfma16(a[fi], b[fj], sacc[fi][fj]);
  }

  const int widx = win & 63;
  const int wh = widx >> 3, ww = widx & 7;
  const float scale = 0.17677669529663687f;  // 32^-0.5
#pragma unroll
  for (int fi = 0; fi < 4; fi++) {
#pragma unroll
    for (int reg = 0; reg < 4; reg++) {
      int row = fi * 16 + lq * 4 + reg;  // C/D: row=(l>>4)*4+reg (+fi*16)
      int i1 = row >> 3, j1 = row & 7;
      int ly1 = (wh == 7) ? (i1 >= 4 ? 2 : 1) : 0;
      int lx1 = (ww == 7) ? (j1 >= 4 ? 2 : 1) : 0;
      float vals[4], m = -1e30f;
#pragma unroll
      for (int fj = 0; fj < 4; fj++) {
        int col = fj * 16 + lr;  // C/D: col=l&15 (+fj*16)
        int i2 = col >> 3, j2 = col & 7;
        float v = sacc[fi][fj][reg] * scale +
                  btab[((i1 - i2 + 7) * 15 + (j1 - j2 + 7)) * 12 + h];
        int ly2 = (wh == 7) ? (i2 >= 4 ? 2 : 1) : 0;
        int lx2 = (ww == 7) ? (j2 >= 4 ? 2 : 1) : 0;
        if (ly1 != ly2 || lx1 != lx2) v -= 100.f;
        vals[fj] = v;
        m = fmaxf(m, v);
      }
#pragma unroll
      for (int o = 1; o < 16; o <<= 1) m = fmaxf(m, __shfl_xor(m, o));
      float ssum = 0.f;
#pragma unroll
      for (int fj = 0; fj < 4; fj++) {
        vals[fj] = __expf(vals[fj] - m);
        ssum += vals[fj];
      }
#pragma unroll
      for (int o = 1; o < 16; o <<= 1) ssum += __shfl_xor(ssum, o);
      float inv = 1.f / ssum;
      int sw = (row & 7) << 3;
#pragma unroll
      for (int fj = 0; fj < 4; fj++)
        Ps[row * 64 + ((fj * 16 + lr) ^ sw)] = (bf16_t)(vals[fj] * inv);
    }
  }
  __syncthreads();

  // O = P V  (64x32, K=64); swizzled Ps / Vt reads (conflict-free)
  f32x4 oacc[4][2] = {};
#pragma unroll
  for (int kc = 0; kc < 2; kc++) {
    bf16x8 pa[4], vb[2];
#pragma unroll
    for (int fi = 0; fi < 4; fi++) {
      int row = fi * 16 + lr;
      pa[fi] = *(const bf16x8*)&Ps[row * 64 + ((kc * 32 + lq * 8) ^ ((row & 7) << 3))];
    }
#pragma unroll
    for (int fj = 0; fj < 2; fj++) {
      int row = fj * 16 + lr;
      vb[fj] = *(const bf16x8*)&Vt[row * 64 + ((kc * 32 + lq * 8) ^ ((row & 7) << 3))];
    }
#pragma unroll
    for (int fi = 0; fi < 4; fi++)
#pragma unroll
      for (int fj = 0; fj < 2; fj++)
        oacc[fi][fj] = mfma16(pa[fi], vb[fj], oacc[fi][fj]);
  }
#pragma unroll
  for (int fi = 0; fi < 4; fi++)
#pragma unroll
    for (int reg = 0; reg < 4; reg++) {
      int row = fi * 16 + lq * 4 + reg;
      size_t rb = ((size_t)win * 64 + row) * 384 + h * 32;
#pragma unroll
      for (int fj = 0; fj < 2; fj++)
        aout[rb + fj * 16 + lr] = (bf16_t)oacc[fi][fj][reg];
    }
}

// ---------------------------------------------------------------------------
extern "C" void kernel_launch(void* const* d_in, const int* in_sizes, int n_in,
                              void* d_out, int out_size, void* d_ws, size_t ws_size,
                              hipStream_t stream) {
  (void)in_sizes; (void)n_in; (void)out_size; (void)ws_size;
  const float* x      = (const float*)d_in[0];
  const float* gamma1 = (const float*)d_in[1];
  const float* beta1  = (const float*)d_in[2];
  const float* w_qkv  = (const float*)d_in[3];
  const float* b_qkv  = (const float*)d_in[4];
  const float* btab   = (const float*)d_in[5];
  const float* w_proj = (const float*)d_in[6];
  const float* b_proj = (const float*)d_in[7];
  const float* gamma2 = (const float*)d_in[8];
  const float* beta2  = (const float*)d_in[9];
  const float* w_fc1  = (const float*)d_in[10];
  const float* b_fc1  = (const float*)d_in[11];
  const float* w_fc2  = (const float*)d_in[12];
  const float* b_fc2  = (const float*)d_in[13];
  float* out = (float*)d_out;

  char* ws = (char*)d_ws;
  size_t off = 0;
  auto alloc = [&](size_t bytes) {
    void* p = ws + off;
    off += (bytes + 255) & ~(size_t)255;
    return p;
  };
  bf16_t* wqkvT  = (bf16_t*)alloc((size_t)1152 * 384 * 2);
  bf16_t* wprojT = (bf16_t*)alloc((size_t)384 * 384 * 2);
  bf16_t* wfc1T  = (bf16_t*)alloc((size_t)1536 * 384 * 2);
  bf16_t* wfc2T  = (bf16_t*)alloc((size_t)384 * 1536 * 2);
  // qkv rows [TOK][1152] alias mlp hidden [TOK][1536]; lifetimes disjoint.
  char* big = (char*)alloc((size_t)TOK * 1536 * 2);
  bf16_t* bufA = (bf16_t*)big;  // qkv rows
  bf16_t* bufH = (bf16_t*)big;  // mlp hidden
  bf16_t* bufB = (bf16_t*)alloc((size_t)TOK * 384 * 2);  // ln1/attn/ln2 rows

  wconv_kernel<<<(1152 * 384 + 255) / 256, 256, 0, stream>>>(w_qkv, wqkvT, 384, 1152);
  wconv_kernel<<<(384 * 384 + 255) / 256, 256, 0, stream>>>(w_proj, wprojT, 384, 384);
  wconv_kernel<<<(384 * 1536 + 255) / 256, 256, 0, stream>>>(w_fc1, wfc1T, 384, 1536);
  wconv_kernel<<<(1536 * 384 + 255) / 256, 256, 0, stream>>>(w_fc2, wfc2T, 1536, 384);

  // LN1 + roll + window partition -> bufB [131072][384] bf16
  ln_kernel<1><<<TOK / 4, 256, 0, stream>>>(x, gamma1, beta1, bufB);
  // QKV: [131072,384] x [384,1152] -> bufA bf16   (grid 9*1024, %8==0)
  gemm_bt<0><<<9 * (TOK / 128), 256, 0, stream>>>(
      bufB, wqkvT, b_qkv, 384, 1152, 9, bufA, nullptr, nullptr);
  // windowed attention -> bufB [131072][384] bf16
  attn_kernel<<<dim3(NWIN, 12), 64, 0, stream>>>(bufA, btab, bufB);
  // proj + un-roll scatter + residual(x) -> out (x1, f32)  (grid 3*1024)
  gemm_bt<2><<<3 * (TOK / 128), 256, 0, stream>>>(
      bufB, wprojT, b_proj, 384, 384, 3, nullptr, out, x);
  // LN2 -> bufB bf16
  ln_kernel<0><<<TOK / 4, 256, 0, stream>>>(out, gamma2, beta2, bufB);
  // FC1 + fast GELU -> bufH [131072][1536] bf16  (grid 12*1024)
  gemm_bt<1><<<12 * (TOK / 128), 256, 0, stream>>>(
      bufB, wfc1T, b_fc1, 384, 1536, 12, bufH, nullptr, nullptr);
  // FC2 + residual(out, in-place) -> out  (grid 3*1024)
  gemm_bt<3><<<3 * (TOK / 128), 256, 0, stream>>>(
      bufH, wfc2T, b_fc2, 1536, 384, 3, nullptr, out, out);
}

// Round 9
// 1215.274 us; speedup vs baseline: 1.8483x; 1.2321x over previous
//
#include <hip/hip_runtime.h>
#include <hip/hip_bf16.h>

typedef __bf16 bf16_t;
typedef __bf16 bf16x8 __attribute__((ext_vector_type(8)));
typedef float f32x4 __attribute__((ext_vector_type(4)));

#define DI __device__ __forceinline__

static constexpr int TOK = 131072;  // 32 batches * 64*64 tokens
static constexpr int NWIN = 2048;   // 32 * 64 windows

// window-order token t -> source image token (LN1 gather) == proj scatter dest.
DI int src_token(int t) {
  int b = t >> 12;
  int widx = (t >> 6) & 63;
  int n = t & 63;
  int wh = widx >> 3, ww = widx & 7;
  int i = n >> 3, j = n & 7;
  int y = ((wh << 3) + i + 4) & 63;
  int x2 = ((ww << 3) + j + 4) & 63;
  return (b << 12) + (y << 6) + x2;
}

DI f32x4 mfma16(bf16x8 a, bf16x8 b, f32x4 c) {
  return __builtin_amdgcn_mfma_f32_16x16x32_bf16(a, b, c, 0, 0, 0);
}

DI void gload_lds16(const bf16_t* g, bf16_t* l) {
  __builtin_amdgcn_global_load_lds(
      (__attribute__((address_space(1))) void*)const_cast<bf16_t*>(g),
      (__attribute__((address_space(3))) void*)l, 16, 0, 0);
}

// ---------------- weight transpose+convert: w[K][N] f32 -> wt[N][K] bf16 ----
__global__ void wconv_kernel(const float* __restrict__ w, bf16_t* __restrict__ wt,
                             int K, int N) {
  int idx = blockIdx.x * 256 + threadIdx.x;
  if (idx >= N * K) return;
  int n = idx / K, k = idx - n * K;
  wt[idx] = (bf16_t)w[(size_t)k * N + n];
}

// ---------------- LayerNorm (+optional shift/partition gather), f32 -> bf16 --
template <int MAP>
__global__ __launch_bounds__(256)
void ln_kernel(const float* __restrict__ xin, const float* __restrict__ g,
               const float* __restrict__ be, bf16_t* __restrict__ out) {
  int w = threadIdx.x >> 6, l = threadIdx.x & 63;
  int t = blockIdx.x * 4 + w;
  int s = MAP ? src_token(t) : t;
  const float* row = xin + (size_t)s * 384;
  float v[6], s1 = 0.f, s2 = 0.f;
#pragma unroll
  for (int i = 0; i < 6; i++) {
    v[i] = row[l + i * 64];
    s1 += v[i];
    s2 += v[i] * v[i];
  }
#pragma unroll
  for (int o = 32; o; o >>= 1) {
    s1 += __shfl_xor(s1, o);
    s2 += __shfl_xor(s2, o);
  }
  float mean = s1 * (1.f / 384.f);
  float var = s2 * (1.f / 384.f) - mean * mean;
  float rs = rsqrtf(var + 1e-5f);
  bf16_t* orow = out + (size_t)t * 384;
#pragma unroll
  for (int i = 0; i < 6; i++) {
    int idx = l + i * 64;
    orow[idx] = (bf16_t)((v[i] - mean) * rs * g[idx] + be[idx]);
  }
}

// ---------------- GEMM: C[M][N] = A[M][K]*Wt[N][K]^T + bias ------------------
// Round-6 proven sync structure (single-buffered 32KB LDS, BK=64, 2 barriers
// per K-tile, both-sides XOR swizzle, XCD-chunked remap) + round-8's proven
// VALU diet (VALUBusy 42%->9%): precomputed swizzled ds_read offsets,
// lane-only staging source with pointer-bump, hoisted bias.
// MODE 0: bf16 out. 1: bf16 gelu(out). 2: f32 scatter(src_token)+resid.
// MODE 3: f32 +resid (resid aliases outf; element owned by one thread).
template <int MODE>
__global__ __launch_bounds__(256, 4)
void gemm_bt(const bf16_t* __restrict__ A, const bf16_t* __restrict__ Wt,
             const float* __restrict__ bias, int K, int ldout, int ncols,
             bf16_t* outb, float* outf, const float* resid) {
  __shared__ __align__(16) bf16_t Alds[128 * 64];
  __shared__ __align__(16) bf16_t Blds[128 * 64];
  const int tid = threadIdx.x;
  const int l = tid & 63, w = tid >> 6;
  const int lr = l & 15, lq = l >> 4;
  // XCD-chunked bijective remap (nwg % 8 == 0)
  const int nwg = gridDim.x;
  const int orig = blockIdx.x;
  const int wgid = (orig & 7) * (nwg >> 3) + (orig >> 3);
  const int bn = wgid % ncols, bm = wgid / ncols;
  const int wr = w >> 1, wc = w & 1;

  // staging source (lane-dependent, swizzle-inverted): row&7 == l>>3 here,
  // so the inverse-swizzled source column is lane-only.
  const int srow = w * 8 + (l >> 3);
  const int scol = ((l & 7) ^ (l >> 3)) << 3;
  const bf16_t* ga = A + ((size_t)bm * 128 + srow) * K + scol;
  const bf16_t* gb = Wt + ((size_t)bn * 128 + srow) * K + scol;
  const size_t k32 = (size_t)32 * K;
  bf16_t* la = &Alds[w * 512];  // wave-uniform LDS dest base
  bf16_t* lb = &Blds[w * 512];

  // K-invariant swizzled LDS read element-offsets
  int aoff[8], boff[8];
#pragma unroll
  for (int fi = 0; fi < 4; fi++) {
    int ra = wr * 64 + fi * 16 + lr;
    int rb = wc * 64 + fi * 16 + lr;
#pragma unroll
    for (int ks = 0; ks < 2; ks++) {
      aoff[fi * 2 + ks] = ra * 64 + ((ks * 32 + lq * 8) ^ ((ra & 7) << 3));
      boff[fi * 2 + ks] = rb * 64 + ((ks * 32 + lq * 8) ^ ((rb & 7) << 3));
    }
  }

  f32x4 acc[4][4] = {};
  const int nt = K >> 6;
  for (int t = 0; t < nt; t++) {
#pragma unroll
    for (int r = 0; r < 4; r++) {
      gload_lds16(ga + r * k32, la + r * 2048);
      gload_lds16(gb + r * k32, lb + r * 2048);
    }
    ga += 64;
    gb += 64;
    __syncthreads();
#pragma unroll
    for (int ks = 0; ks < 2; ks++) {
      bf16x8 af[4], bfr[4];
#pragma unroll
      for (int fi = 0; fi < 4; fi++)
        af[fi] = *(const bf16x8*)&Alds[aoff[fi * 2 + ks]];
#pragma unroll
      for (int fj = 0; fj < 4; fj++)
        bfr[fj] = *(const bf16x8*)&Blds[boff[fj * 2 + ks]];
#pragma unroll
      for (int fi = 0; fi < 4; fi++)
#pragma unroll
        for (int fj = 0; fj < 4; fj++)
          acc[fi][fj] = mfma16(af[fi], bfr[fj], acc[fi][fj]);
    }
    __syncthreads();
  }

  // ---- epilogue ----
  float bv[4];
#pragma unroll
  for (int fj = 0; fj < 4; fj++)
    bv[fj] = bias[bn * 128 + wc * 64 + fj * 16 + lr];
#pragma unroll
  for (int fi = 0; fi < 4; fi++) {
#pragma unroll
    for (int reg = 0; reg < 4; reg++) {
      int grow = bm * 128 + wr * 64 + fi * 16 + lq * 4 + reg;
      size_t rbase;
      if constexpr (MODE == 2)
        rbase = (size_t)src_token(grow) * ldout;
      else
        rbase = (size_t)grow * ldout;
#pragma unroll
      for (int fj = 0; fj < 4; fj++) {
        int gcol = bn * 128 + wc * 64 + fj * 16 + lr;
        float val = acc[fi][fj][reg] + bv[fj];
        if constexpr (MODE == 0) {
          outb[rbase + gcol] = (bf16_t)val;
        } else if constexpr (MODE == 1) {
          // tanh-form GELU: x * sigmoid(1.59577(x + 0.044715 x^3))
          float z = -1.5957691216f * val * fmaf(0.044715f, val * val, 1.0f);
          val = val / (1.0f + __expf(z));
          outb[rbase + gcol] = (bf16_t)val;
        } else {
          outf[rbase + gcol] = val + resid[rbase + gcol];
        }
      }
    }
  }
}

// ---------------- per-(window, head) attention (staged, swizzled) -----------
__global__ __launch_bounds__(64)
void attn_kernel(const bf16_t* __restrict__ qkv, const float* __restrict__ btab,
                 bf16_t* __restrict__ aout) {
  __shared__ __align__(16) bf16_t Qs[64 * 32];
  __shared__ __align__(16) bf16_t Ks[64 * 32];
  __shared__ __align__(16) bf16_t Vt[32 * 64];
  __shared__ __align__(16) bf16_t Ps[64 * 64];
  const int win = blockIdx.x, h = blockIdx.y;
  const int l = threadIdx.x, lr = l & 15, lq = l >> 4;

  {
    const bf16_t* qrow = qkv + ((size_t)win * 64 + l) * 1152 + h * 32;
#pragma unroll
    for (int c = 0; c < 4; c++) {
      *(bf16x8*)&Qs[l * 32 + c * 8] = *(const bf16x8*)&qrow[c * 8];
      *(bf16x8*)&Ks[l * 32 + c * 8] = *(const bf16x8*)&qrow[384 + c * 8];
    }
#pragma unroll
    for (int c = 0; c < 4; c++) {
      bf16x8 tv = *(const bf16x8*)&qrow[768 + c * 8];
#pragma unroll
      for (int e = 0; e < 8; e++) {
        int vr = c * 8 + e;
        Vt[vr * 64 + (l ^ ((vr & 7) << 3))] = tv[e];  // swizzled col
      }
    }
  }
  __syncthreads();

  // S = Q K^T  (64x64, K=32)
  f32x4 sacc[4][4] = {};
  {
    bf16x8 a[4], b[4];
#pragma unroll
    for (int fi = 0; fi < 4; fi++)
      a[fi] = *(const bf16x8*)&Qs[(fi * 16 + lr) * 32 + lq * 8];
#pragma unroll
    for (int fj = 0; fj < 4; fj++)
      b[fj] = *(const bf16x8*)&Ks[(fj * 16 + lr) * 32 + lq * 8];
#pragma unroll
    for (int fi = 0; fi < 4; fi++)
#pragma unroll
      for (int fj = 0; fj < 4; fj++)
        sacc[fi][fj] = mfma16(a[fi], b[fj], sacc[fi][fj]);
  }

  const int widx = win & 63;
  const int wh = widx >> 3, ww = widx & 7;
  const float scale = 0.17677669529663687f;  // 32^-0.5
#pragma unroll
  for (int fi = 0; fi < 4; fi++) {
#pragma unroll
    for (int reg = 0; reg < 4; reg++) {
      int row = fi * 16 + lq * 4 + reg;  // C/D: row=(l>>4)*4+reg (+fi*16)
      int i1 = row >> 3, j1 = row & 7;
      int ly1 = (wh == 7) ? (i1 >= 4 ? 2 : 1) : 0;
      int lx1 = (ww == 7) ? (j1 >= 4 ? 2 : 1) : 0;
      float vals[4], m = -1e30f;
#pragma unroll
      for (int fj = 0; fj < 4; fj++) {
        int col = fj * 16 + lr;  // C/D: col=l&15 (+fj*16)
        int i2 = col >> 3, j2 = col & 7;
        float v = sacc[fi][fj][reg] * scale +
                  btab[((i1 - i2 + 7) * 15 + (j1 - j2 + 7)) * 12 + h];
        int ly2 = (wh == 7) ? (i2 >= 4 ? 2 : 1) : 0;
        int lx2 = (ww == 7) ? (j2 >= 4 ? 2 : 1) : 0;
        if (ly1 != ly2 || lx1 != lx2) v -= 100.f;
        vals[fj] = v;
        m = fmaxf(m, v);
      }
#pragma unroll
      for (int o = 1; o < 16; o <<= 1) m = fmaxf(m, __shfl_xor(m, o));
      float ssum = 0.f;
#pragma unroll
      for (int fj = 0; fj < 4; fj++) {
        vals[fj] = __expf(vals[fj] - m);
        ssum += vals[fj];
      }
#pragma unroll
      for (int o = 1; o < 16; o <<= 1) ssum += __shfl_xor(ssum, o);
      float inv = 1.f / ssum;
      int sw = (row & 7) << 3;
#pragma unroll
      for (int fj = 0; fj < 4; fj++)
        Ps[row * 64 + ((fj * 16 + lr) ^ sw)] = (bf16_t)(vals[fj] * inv);
    }
  }
  __syncthreads();

  // O = P V  (64x32, K=64); swizzled Ps / Vt reads (conflict-free)
  f32x4 oacc[4][2] = {};
#pragma unroll
  for (int kc = 0; kc < 2; kc++) {
    bf16x8 pa[4], vb[2];
#pragma unroll
    for (int fi = 0; fi < 4; fi++) {
      int row = fi * 16 + lr;
      pa[fi] = *(const bf16x8*)&Ps[row * 64 + ((kc * 32 + lq * 8) ^ ((row & 7) << 3))];
    }
#pragma unroll
    for (int fj = 0; fj < 2; fj++) {
      int row = fj * 16 + lr;
      vb[fj] = *(const bf16x8*)&Vt[row * 64 + ((kc * 32 + lq * 8) ^ ((row & 7) << 3))];
    }
#pragma unroll
    for (int fi = 0; fi < 4; fi++)
#pragma unroll
      for (int fj = 0; fj < 2; fj++)
        oacc[fi][fj] = mfma16(pa[fi], vb[fj], oacc[fi][fj]);
  }
#pragma unroll
  for (int fi = 0; fi < 4; fi++)
#pragma unroll
    for (int reg = 0; reg < 4; reg++) {
      int row = fi * 16 + lq * 4 + reg;
      size_t rb = ((size_t)win * 64 + row) * 384 + h * 32;
#pragma unroll
      for (int fj = 0; fj < 2; fj++)
        aout[rb + fj * 16 + lr] = (bf16_t)oacc[fi][fj][reg];
    }
}

// ---------------------------------------------------------------------------
extern "C" void kernel_launch(void* const* d_in, const int* in_sizes, int n_in,
                              void* d_out, int out_size, void* d_ws, size_t ws_size,
                              hipStream_t stream) {
  (void)in_sizes; (void)n_in; (void)out_size; (void)ws_size;
  const float* x      = (const float*)d_in[0];
  const float* gamma1 = (const float*)d_in[1];
  const float* beta1  = (const float*)d_in[2];
  const float* w_qkv  = (const float*)d_in[3];
  const float* b_qkv  = (const float*)d_in[4];
  const float* btab   = (const float*)d_in[5];
  const float* w_proj = (const float*)d_in[6];
  const float* b_proj = (const float*)d_in[7];
  const float* gamma2 = (const float*)d_in[8];
  const float* beta2  = (const float*)d_in[9];
  const float* w_fc1  = (const float*)d_in[10];
  const float* b_fc1  = (const float*)d_in[11];
  const float* w_fc2  = (const float*)d_in[12];
  const float* b_fc2  = (const float*)d_in[13];
  float* out = (float*)d_out;

  char* ws = (char*)d_ws;
  size_t off = 0;
  auto alloc = [&](size_t bytes) {
    void* p = ws + off;
    off += (bytes + 255) & ~(size_t)255;
    return p;
  };
  bf16_t* wqkvT  = (bf16_t*)alloc((size_t)1152 * 384 * 2);
  bf16_t* wprojT = (bf16_t*)alloc((size_t)384 * 384 * 2);
  bf16_t* wfc1T  = (bf16_t*)alloc((size_t)1536 * 384 * 2);
  bf16_t* wfc2T  = (bf16_t*)alloc((size_t)384 * 1536 * 2);
  // qkv rows [TOK][1152] alias mlp hidden [TOK][1536]; lifetimes disjoint.
  char* big = (char*)alloc((size_t)TOK * 1536 * 2);
  bf16_t* bufA = (bf16_t*)big;  // qkv rows
  bf16_t* bufH = (bf16_t*)big;  // mlp hidden
  bf16_t* bufB = (bf16_t*)alloc((size_t)TOK * 384 * 2);  // ln1/attn/ln2 rows

  wconv_kernel<<<(1152 * 384 + 255) / 256, 256, 0, stream>>>(w_qkv, wqkvT, 384, 1152);
  wconv_kernel<<<(384 * 384 + 255) / 256, 256, 0, stream>>>(w_proj, wprojT, 384, 384);
  wconv_kernel<<<(384 * 1536 + 255) / 256, 256, 0, stream>>>(w_fc1, wfc1T, 384, 1536);
  wconv_kernel<<<(1536 * 384 + 255) / 256, 256, 0, stream>>>(w_fc2, wfc2T, 1536, 384);

  // LN1 + roll + window partition -> bufB [131072][384] bf16
  ln_kernel<1><<<TOK / 4, 256, 0, stream>>>(x, gamma1, beta1, bufB);
  // QKV: [131072,384] x [384,1152] -> bufA bf16   (grid 9*1024, %8==0)
  gemm_bt<0><<<9 * (TOK / 128), 256, 0, stream>>>(
      bufB, wqkvT, b_qkv, 384, 1152, 9, bufA, nullptr, nullptr);
  // windowed attention -> bufB [131072][384] bf16
  attn_kernel<<<dim3(NWIN, 12), 64, 0, stream>>>(bufA, btab, bufB);
  // proj + un-roll scatter + residual(x) -> out (x1, f32)  (grid 3*1024)
  gemm_bt<2><<<3 * (TOK / 128), 256, 0, stream>>>(
      bufB, wprojT, b_proj, 384, 384, 3, nullptr, out, x);
  // LN2 -> bufB bf16
  ln_kernel<0><<<TOK / 4, 256, 0, stream>>>(out, gamma2, beta2, bufB);
  // FC1 + fast GELU -> bufH [131072][1536] bf16  (grid 12*1024)
  gemm_bt<1><<<12 * (TOK / 128), 256, 0, stream>>>(
      bufB, wfc1T, b_fc1, 384, 1536, 12, bufH, nullptr, nullptr);
  // FC2 + residual(out, in-place) -> out  (grid 3*1024)
  gemm_bt<3><<<3 * (TOK / 128), 256, 0, stream>>>(
      bufH, wfc2T, b_fc2, 1536, 384, 3, nullptr, out, out);
}